// Round 4
// baseline (996.682 us; speedup 1.0000x reference)
//
#include <hip/hip_runtime.h>
#include <hip/hip_bf16.h>
#include <math.h>

#define N_USERS 50000
#define N_ITEMS 50000
#define N_NODES 100000
#define DIM 64
#define BATCH 2048
#define SLOTS 4096

using frag_ab = __attribute__((ext_vector_type(8))) short;  // 8 bf16
using frag_cd = __attribute__((ext_vector_type(4))) float;  // 4 fp32

// ---------------- helpers ----------------

__device__ __forceinline__ float wave_reduce_sum(float v) {
#pragma unroll
  for (int off = 32; off > 0; off >>= 1)
    v += __shfl_xor(v, off, 64);
  return v;
}

__device__ __forceinline__ int wave_reduce_sum_i(int v) {
#pragma unroll
  for (int off = 32; off > 0; off >>= 1)
    v += __shfl_xor(v, off, 64);
  return v;
}

__device__ __forceinline__ int wave_incl_scan_i(int v, int lane) {
#pragma unroll
  for (int off = 1; off < 64; off <<= 1) {
    int t = __shfl_up(v, off, 64);
    if (lane >= off) v += t;
  }
  return v;
}

__device__ __forceinline__ const float* ego_row(const float* ue, const float* ie, int n) {
  return (n < N_USERS) ? (ue + (size_t)n * DIM) : (ie + (size_t)(n - N_USERS) * DIM);
}

__device__ __forceinline__ ushort f2bf(float x) {
  __hip_bfloat16 h = __float2bfloat16(x);
  return *(ushort*)&h;
}

__device__ __forceinline__ float bf2f(ushort u) {
  return __uint_as_float(((unsigned)u) << 16);
}

// ---------------- small setup kernels ----------------

__global__ void build_map_kernel(const int* __restrict__ nu, const int* __restrict__ ni,
                                 int* __restrict__ map) {
  int s = blockIdx.x * blockDim.x + threadIdx.x;
  if (s >= SLOTS) return;
  int n = (s < BATCH) ? nu[s] : (N_USERS + ni[s - BATCH]);
  map[n] = s;
}

// ego -> bf16 (concatenated node-major table xb[100000][64])
__global__ void ego2bf_kernel(const float* __restrict__ ue, const float* __restrict__ ie,
                              ushort* __restrict__ xb) {
  int t = blockIdx.x * blockDim.x + threadIdx.x;  // index of float4 group
  const int TOT = N_NODES * DIM / 4;
  if (t >= TOT) return;
  const int UH = N_USERS * DIM / 4;
  float4 f = (t < UH) ? ((const float4*)ue)[t] : ((const float4*)ie)[t - UH];
  ushort4 o;
  o.x = f2bf(f.x); o.y = f2bf(f.y); o.z = f2bf(f.z); o.w = f2bf(f.w);
  ((ushort4*)xb)[t] = o;
}

// ---------------- CSR build for graph 2 ----------------

__global__ void hist_kernel(const int* __restrict__ rows, int* __restrict__ deg, int nE) {
  int e = blockIdx.x * blockDim.x + threadIdx.x;
  if (e >= nE) return;
  atomicAdd(&deg[rows[e]], 1);
}

// per-1024-chunk sums
__global__ void scan_p1_kernel(const int* __restrict__ deg, int* __restrict__ bsum) {
  int b = blockIdx.x, t = threadIdx.x;
  int lane = t & 63, wave = t >> 6;
  int base = b * 1024 + t * 4;
  int s = 0;
#pragma unroll
  for (int k = 0; k < 4; k++) {
    int i = base + k;
    if (i < N_NODES) s += deg[i];
  }
  s = wave_reduce_sum_i(s);
  __shared__ int ws[4];
  if (lane == 0) ws[wave] = s;
  __syncthreads();
  if (t == 0) bsum[b] = ws[0] + ws[1] + ws[2] + ws[3];
}

// exclusive scan of the 98 chunk sums (single wave)
__global__ void scan_p2_kernel(int* __restrict__ bsum, int nchunks) {
  int lane = threadIdx.x;
  int v0 = (lane < nchunks) ? bsum[lane] : 0;
  int v1 = (64 + lane < nchunks) ? bsum[64 + lane] : 0;
  int i0 = wave_incl_scan_i(v0, lane);
  int tot0 = __shfl(i0, 63, 64);
  int i1 = wave_incl_scan_i(v1, lane);
  int e0 = i0 - v0;
  int e1 = tot0 + i1 - v1;
  if (lane < nchunks) bsum[lane] = e0;
  if (64 + lane < nchunks) bsum[64 + lane] = e1;
}

// block-level exclusive scan + chunk offset -> rowptr, cursor
__global__ void scan_p3_kernel(const int* __restrict__ deg, const int* __restrict__ bsum,
                               int* __restrict__ rowptr, int* __restrict__ cursor) {
  int b = blockIdx.x, t = threadIdx.x;
  int lane = t & 63, wave = t >> 6;
  int base = b * 1024 + t * 4;
  int d[4];
#pragma unroll
  for (int k = 0; k < 4; k++) {
    int i = base + k;
    d[k] = (i < N_NODES) ? deg[i] : 0;
  }
  int tsum = d[0] + d[1] + d[2] + d[3];
  int incl = wave_incl_scan_i(tsum, lane);
  __shared__ int wtot[4];
  if (lane == 63) wtot[wave] = incl;
  __syncthreads();
  int woff = 0;
  for (int w = 0; w < wave; w++) woff += wtot[w];
  int run = bsum[b] + woff + incl - tsum;
#pragma unroll
  for (int k = 0; k < 4; k++) {
    int i = base + k;
    if (i < N_NODES) {
      rowptr[i] = run;
      cursor[i] = run;
      if (i == N_NODES - 1) rowptr[N_NODES] = run + d[k];
    }
    run += d[k];
  }
}

__global__ void scatter_kernel(const int* __restrict__ rows, const int* __restrict__ cols,
                               const float* __restrict__ vals, int* __restrict__ cursor,
                               int2* __restrict__ pack, int nE) {
  int e = blockIdx.x * blockDim.x + threadIdx.x;
  if (e >= nE) return;
  int r = rows[e];
  int pos = atomicAdd(&cursor[r], 1);
  pack[pos] = make_int2(cols[e], __float_as_int(vals[e]));
}

// gather SpMM (fp32 acc, bf16 x) + 0.5*(ego+.) + l2norm -> zallb. One wave/node.
__global__ void gather_norm_kernel(const int* __restrict__ rowptr, const int2* __restrict__ pack,
                                   const ushort* __restrict__ xb, const float* __restrict__ ue,
                                   const float* __restrict__ ie, ushort* __restrict__ zallb) {
  int n = blockIdx.x * 4 + (threadIdx.x >> 6);
  if (n >= N_NODES) return;
  int lane = threadIdx.x & 63;
  int k = rowptr[n], kend = rowptr[n + 1];
  float acc = 0.f;
  for (; k + 2 <= kend; k += 2) {
    int2 p0 = pack[k];
    int2 p1 = pack[k + 1];
    float x0 = bf2f(xb[(size_t)p0.x * DIM + lane]);
    float x1 = bf2f(xb[(size_t)p1.x * DIM + lane]);
    acc = fmaf(__int_as_float(p0.y), x0, acc);
    acc = fmaf(__int_as_float(p1.y), x1, acc);
  }
  if (k < kend) {
    int2 p = pack[k];
    acc = fmaf(__int_as_float(p.y), bf2f(xb[(size_t)p.x * DIM + lane]), acc);
  }
  const float* eg = ego_row(ue, ie, n);
  float v = 0.5f * (eg[lane] + acc);
  float ss = wave_reduce_sum(v * v);
  float z = v / fmaxf(sqrtf(ss), 1e-12f);
  zallb[(size_t)n * DIM + lane] = f2bf(z);
}

// ---------------- graph 1 (filter -> compact -> accumulate) ----------------

// One THREAD per edge: probe map, push hits into compacted list.
// flagged entry: {(slot<<17)|col, val_bits}  (col<2^17, slot<2^12)
__global__ void filter1_kernel(const int* __restrict__ rows, const int* __restrict__ cols,
                               const float* __restrict__ vals, const int* __restrict__ map,
                               int* __restrict__ count, int2* __restrict__ flagged, int nE) {
  int e = blockIdx.x * blockDim.x + threadIdx.x;
  if (e >= nE) return;
  int r = rows[e];
  int s = map[r];
  if (s < 0) return;
  int pos = atomicAdd(count, 1);
  flagged[pos] = make_int2((s << 17) | cols[e], __float_as_int(vals[e]));
}

// Persistent waves grid-stride the flagged list; 64-lane atomic accumulate.
__global__ void accum1_kernel(const int2* __restrict__ flagged, const int* __restrict__ count,
                              const ushort* __restrict__ xb, float* __restrict__ z1acc) {
  int gwave = (blockIdx.x * blockDim.x + threadIdx.x) >> 6;
  int nwaves = (gridDim.x * blockDim.x) >> 6;
  int lane = threadIdx.x & 63;
  int n = *count;
  for (int k = gwave; k < n; k += nwaves) {
    int2 p = flagged[k];
    int c = p.x & 0x1FFFF;
    int s = p.x >> 17;
    float v = __int_as_float(p.y);
    float x = bf2f(xb[(size_t)c * DIM + lane]);
    unsafeAtomicAdd(&z1acc[(size_t)s * DIM + lane], v * x);
  }
}

// z1 normalize (fp32) -> bf16; pos term out -= dot(z1, z2) with z2 from zallb.
__global__ void gather1_kernel(const float* __restrict__ ue, const float* __restrict__ ie,
                               const int* __restrict__ nu, const int* __restrict__ ni,
                               const int* __restrict__ map, const float* __restrict__ z1acc,
                               const ushort* __restrict__ zallb, ushort* __restrict__ z1b,
                               float* __restrict__ out) {
  int s = blockIdx.x * 4 + (threadIdx.x >> 6);
  if (s >= SLOTS) return;
  int lane = threadIdx.x & 63;
  int n = (s < BATCH) ? nu[s] : (N_USERS + ni[s - BATCH]);
  int fs = map[n];
  const float* e = ego_row(ue, ie, n);
  float v = 0.5f * (e[lane] + z1acc[(size_t)fs * DIM + lane]);
  float ss = wave_reduce_sum(v * v);
  float z = v / fmaxf(sqrtf(ss), 1e-12f);
  z1b[(size_t)s * DIM + lane] = f2bf(z);
  float dp = wave_reduce_sum(z * bf2f(zallb[(size_t)n * DIM + lane]));
  if (lane == 0) atomicAdd(out, -dp);
}

// ---------------- ttl (bf16 MFMA) ----------------
// Wave tile: M=32 z1 rows x 16 j per chunk, K=64 -> 4 MFMAs/chunk.
// Block = 4 waves = 128 rows, one strip of 25 chunks (400 j). Grid 32x125.
#define TTL_STRIPS 125
#define TTL_CHUNKS 25
__global__ __launch_bounds__(256) void ttl_mfma_kernel(const ushort* __restrict__ z1b,
                                                       const ushort* __restrict__ zallb,
                                                       float* __restrict__ ttl) {
  int rb = blockIdx.x / TTL_STRIPS;
  int strip = blockIdx.x % TTL_STRIPS;
  int wave = threadIdx.x >> 6;
  int lane = threadIdx.x & 63;
  int r0 = rb * 128 + wave * 32;
  int side = r0 >> 11;  // rows 0..2047 users, 2048..4095 items
  const ushort* zs = zallb + (size_t)side * N_USERS * DIM;

  int m = lane & 15, q = lane >> 4;
  const ushort* ar0 = z1b + (size_t)(r0 + m) * DIM + q * 8;
  frag_ab a00 = *(const frag_ab*)ar0;
  frag_ab a01 = *(const frag_ab*)(ar0 + 32);
  const ushort* ar1 = ar0 + 16 * DIM;
  frag_ab a10 = *(const frag_ab*)ar1;
  frag_ab a11 = *(const frag_ab*)(ar1 + 32);

  int j0 = strip * (TTL_CHUNKS * 16);
  const ushort* bp = zs + (size_t)(j0 + m) * DIM + q * 8;

  // depth-2 register pipeline on B
  frag_ab b0c = *(const frag_ab*)bp;
  frag_ab b1c = *(const frag_ab*)(bp + 32);
  const ushort* bp1 = bp + 16 * DIM;
  frag_ab b0n = *(const frag_ab*)bp1;
  frag_ab b1n = *(const frag_ab*)(bp1 + 32);

  float racc[8] = {0.f, 0.f, 0.f, 0.f, 0.f, 0.f, 0.f, 0.f};

  for (int c = 0; c < TTL_CHUNKS; c++) {
    frag_ab b0f = b0c, b1f = b1c;
    if (c + 2 < TTL_CHUNKS) {
      const ushort* bp2 = bp + 2 * 16 * DIM;
      b0f = *(const frag_ab*)bp2;
      b1f = *(const frag_ab*)(bp2 + 32);
    }
    frag_cd acc0 = {}, acc1 = {};
    acc0 = __builtin_amdgcn_mfma_f32_16x16x32_bf16(a00, b0c, acc0, 0, 0, 0);
    acc0 = __builtin_amdgcn_mfma_f32_16x16x32_bf16(a01, b1c, acc0, 0, 0, 0);
    acc1 = __builtin_amdgcn_mfma_f32_16x16x32_bf16(a10, b0c, acc1, 0, 0, 0);
    acc1 = __builtin_amdgcn_mfma_f32_16x16x32_bf16(a11, b1c, acc1, 0, 0, 0);
#pragma unroll
    for (int r = 0; r < 4; r++) {
      racc[r] += __expf(2.f * acc0[r]);
      racc[4 + r] += __expf(2.f * acc1[r]);
    }
    b0c = b0n; b1c = b1n;
    b0n = b0f; b1n = b1f;
    bp += 16 * DIM;
  }

  // C layout: col(=zall j) = lane&15, row(=z1 row) = q*4+reg. Reduce over j lanes.
#pragma unroll
  for (int h = 0; h < 2; h++) {
#pragma unroll
    for (int r = 0; r < 4; r++) {
      float v = racc[h * 4 + r];
      v += __shfl_xor(v, 1, 64);
      v += __shfl_xor(v, 2, 64);
      v += __shfl_xor(v, 4, 64);
      v += __shfl_xor(v, 8, 64);
      if (m == 0) atomicAdd(&ttl[r0 + h * 16 + q * 4 + r], v);
    }
  }
}

// out += 0.5 * sum_i log(ttl[i])
__global__ void final_kernel(const float* __restrict__ ttl, float* __restrict__ out) {
  int t = blockIdx.x * blockDim.x + threadIdx.x;
  float v = (t < SLOTS) ? 0.5f * logf(ttl[t]) : 0.f;
  v = wave_reduce_sum(v);
  if ((threadIdx.x & 63) == 0) atomicAdd(out, v);
}

// ---------------- launch ----------------

extern "C" void kernel_launch(void* const* d_in, const int* in_sizes, int n_in,
                              void* d_out, int out_size, void* d_ws, size_t ws_size,
                              hipStream_t stream) {
  const float* ue = (const float*)d_in[0];
  const float* ie = (const float*)d_in[1];
  const int* rows1 = (const int*)d_in[2];
  const int* cols1 = (const int*)d_in[3];
  const float* vals1 = (const float*)d_in[4];
  const int* rows2 = (const int*)d_in[5];
  const int* cols2 = (const int*)d_in[6];
  const float* vals2 = (const float*)d_in[7];
  const int* nu = (const int*)d_in[8];
  const int* ni = (const int*)d_in[9];
  int nE1 = in_sizes[2], nE2 = in_sizes[5];

  // workspace carve-out (256B aligned), total ~45 MB
  char* ws = (char*)d_ws;
  size_t o = 0;
  auto carve = [&](size_t bytes) {
    char* p = ws + o;
    o += (bytes + 255) & ~(size_t)255;
    return p;
  };
  int* map = (int*)carve(N_NODES * 4);
  float* z1acc = (float*)carve((size_t)SLOTS * DIM * 4);
  float* ttl = (float*)carve(SLOTS * 4);
  ushort* zallb = (ushort*)carve((size_t)N_NODES * DIM * 2);
  ushort* z1b = (ushort*)carve((size_t)SLOTS * DIM * 2);
  ushort* xb = (ushort*)carve((size_t)N_NODES * DIM * 2);
  int* deg = (int*)carve(N_NODES * 4);
  int* rowptr = (int*)carve((N_NODES + 1) * 4);
  int* cursor = (int*)carve(N_NODES * 4);
  int* bsum = (int*)carve(128 * 4);
  int* fcount = (int*)carve(256);
  int2* pack = (int2*)carve((size_t)nE2 * 8);
  int2* flagged = pack;  // alias: pack is dead after gather_norm_kernel
  float* out = (float*)d_out;

  const int NCHUNKS = (N_NODES + 1023) / 1024;  // 98

  hipMemsetAsync(map, 0xFF, N_NODES * 4, stream);  // -1
  hipMemsetAsync(z1acc, 0, (size_t)SLOTS * DIM * 4, stream);
  hipMemsetAsync(ttl, 0, SLOTS * 4, stream);
  hipMemsetAsync(deg, 0, N_NODES * 4, stream);
  hipMemsetAsync(fcount, 0, 4, stream);
  hipMemsetAsync(out, 0, sizeof(float), stream);

  build_map_kernel<<<16, 256, 0, stream>>>(nu, ni, map);
  ego2bf_kernel<<<(N_NODES * DIM / 4 + 255) / 256, 256, 0, stream>>>(ue, ie, xb);
  hist_kernel<<<(nE2 + 255) / 256, 256, 0, stream>>>(rows2, deg, nE2);
  scan_p1_kernel<<<NCHUNKS, 256, 0, stream>>>(deg, bsum);
  scan_p2_kernel<<<1, 64, 0, stream>>>(bsum, NCHUNKS);
  scan_p3_kernel<<<NCHUNKS, 256, 0, stream>>>(deg, bsum, rowptr, cursor);
  scatter_kernel<<<(nE2 + 255) / 256, 256, 0, stream>>>(rows2, cols2, vals2, cursor, pack, nE2);
  gather_norm_kernel<<<(N_NODES + 3) / 4, 256, 0, stream>>>(rowptr, pack, xb, ue, ie, zallb);
  // graph 1 (after gather_norm: flagged aliases pack)
  filter1_kernel<<<(nE1 + 255) / 256, 256, 0, stream>>>(rows1, cols1, vals1, map, fcount, flagged, nE1);
  accum1_kernel<<<1024, 256, 0, stream>>>(flagged, fcount, xb, z1acc);
  gather1_kernel<<<SLOTS / 4, 256, 0, stream>>>(ue, ie, nu, ni, map, z1acc, zallb, z1b, out);
  ttl_mfma_kernel<<<32 * TTL_STRIPS, 256, 0, stream>>>(z1b, zallb, ttl);
  final_kernel<<<16, 256, 0, stream>>>(ttl, out);
}

// Round 5
// 662.079 us; speedup vs baseline: 1.5054x; 1.5054x over previous
//
#include <hip/hip_runtime.h>
#include <hip/hip_bf16.h>
#include <math.h>

#define N_USERS 50000
#define N_ITEMS 50000
#define N_NODES 100000
#define DIM 64
#define BATCH 2048
#define SLOTS 4096

using frag_ab = __attribute__((ext_vector_type(8))) short;  // 8 bf16
using frag_cd = __attribute__((ext_vector_type(4))) float;  // 4 fp32

// ---------------- helpers ----------------

__device__ __forceinline__ float wave_reduce_sum(float v) {
#pragma unroll
  for (int off = 32; off > 0; off >>= 1)
    v += __shfl_xor(v, off, 64);
  return v;
}

__device__ __forceinline__ int wave_reduce_sum_i(int v) {
#pragma unroll
  for (int off = 32; off > 0; off >>= 1)
    v += __shfl_xor(v, off, 64);
  return v;
}

__device__ __forceinline__ int wave_incl_scan_i(int v, int lane) {
#pragma unroll
  for (int off = 1; off < 64; off <<= 1) {
    int t = __shfl_up(v, off, 64);
    if (lane >= off) v += t;
  }
  return v;
}

__device__ __forceinline__ const float* ego_row(const float* ue, const float* ie, int n) {
  return (n < N_USERS) ? (ue + (size_t)n * DIM) : (ie + (size_t)(n - N_USERS) * DIM);
}

__device__ __forceinline__ ushort f2bf(float x) {
  __hip_bfloat16 h = __float2bfloat16(x);
  return *(ushort*)&h;
}

__device__ __forceinline__ float bf2f(ushort u) {
  return __uint_as_float(((unsigned)u) << 16);
}

// ---------------- small setup kernels ----------------

__global__ void build_map_kernel(const int* __restrict__ nu, const int* __restrict__ ni,
                                 int* __restrict__ map) {
  int s = blockIdx.x * blockDim.x + threadIdx.x;
  if (s >= SLOTS) return;
  int n = (s < BATCH) ? nu[s] : (N_USERS + ni[s - BATCH]);
  map[n] = s;
}

// ego -> bf16 (concatenated node-major table xb[100000][64])
__global__ void ego2bf_kernel(const float* __restrict__ ue, const float* __restrict__ ie,
                              ushort* __restrict__ xb) {
  int t = blockIdx.x * blockDim.x + threadIdx.x;  // index of float4 group
  const int TOT = N_NODES * DIM / 4;
  if (t >= TOT) return;
  const int UH = N_USERS * DIM / 4;
  float4 f = (t < UH) ? ((const float4*)ue)[t] : ((const float4*)ie)[t - UH];
  ushort4 o;
  o.x = f2bf(f.x); o.y = f2bf(f.y); o.z = f2bf(f.z); o.w = f2bf(f.w);
  ((ushort4*)xb)[t] = o;
}

// ---------------- CSR build for graph 2 ----------------

__global__ void hist_kernel(const int* __restrict__ rows, int* __restrict__ deg, int nE) {
  int e = blockIdx.x * blockDim.x + threadIdx.x;
  if (e >= nE) return;
  atomicAdd(&deg[rows[e]], 1);
}

// per-1024-chunk sums
__global__ void scan_p1_kernel(const int* __restrict__ deg, int* __restrict__ bsum) {
  int b = blockIdx.x, t = threadIdx.x;
  int lane = t & 63, wave = t >> 6;
  int base = b * 1024 + t * 4;
  int s = 0;
#pragma unroll
  for (int k = 0; k < 4; k++) {
    int i = base + k;
    if (i < N_NODES) s += deg[i];
  }
  s = wave_reduce_sum_i(s);
  __shared__ int ws[4];
  if (lane == 0) ws[wave] = s;
  __syncthreads();
  if (t == 0) bsum[b] = ws[0] + ws[1] + ws[2] + ws[3];
}

// exclusive scan of the 98 chunk sums (single wave)
__global__ void scan_p2_kernel(int* __restrict__ bsum, int nchunks) {
  int lane = threadIdx.x;
  int v0 = (lane < nchunks) ? bsum[lane] : 0;
  int v1 = (64 + lane < nchunks) ? bsum[64 + lane] : 0;
  int i0 = wave_incl_scan_i(v0, lane);
  int tot0 = __shfl(i0, 63, 64);
  int i1 = wave_incl_scan_i(v1, lane);
  int e0 = i0 - v0;
  int e1 = tot0 + i1 - v1;
  if (lane < nchunks) bsum[lane] = e0;
  if (64 + lane < nchunks) bsum[64 + lane] = e1;
}

// block-level exclusive scan + chunk offset -> rowptr, cursor
__global__ void scan_p3_kernel(const int* __restrict__ deg, const int* __restrict__ bsum,
                               int* __restrict__ rowptr, int* __restrict__ cursor) {
  int b = blockIdx.x, t = threadIdx.x;
  int lane = t & 63, wave = t >> 6;
  int base = b * 1024 + t * 4;
  int d[4];
#pragma unroll
  for (int k = 0; k < 4; k++) {
    int i = base + k;
    d[k] = (i < N_NODES) ? deg[i] : 0;
  }
  int tsum = d[0] + d[1] + d[2] + d[3];
  int incl = wave_incl_scan_i(tsum, lane);
  __shared__ int wtot[4];
  if (lane == 63) wtot[wave] = incl;
  __syncthreads();
  int woff = 0;
  for (int w = 0; w < wave; w++) woff += wtot[w];
  int run = bsum[b] + woff + incl - tsum;
#pragma unroll
  for (int k = 0; k < 4; k++) {
    int i = base + k;
    if (i < N_NODES) {
      rowptr[i] = run;
      cursor[i] = run;
      if (i == N_NODES - 1) rowptr[N_NODES] = run + d[k];
    }
    run += d[k];
  }
}

__global__ void scatter_kernel(const int* __restrict__ rows, const int* __restrict__ cols,
                               const float* __restrict__ vals, int* __restrict__ cursor,
                               int2* __restrict__ pack, int nE) {
  int e = blockIdx.x * blockDim.x + threadIdx.x;
  if (e >= nE) return;
  int r = rows[e];
  int pos = atomicAdd(&cursor[r], 1);
  pack[pos] = make_int2(cols[e], __float_as_int(vals[e]));
}

// gather SpMM (fp32 acc, bf16 x) + 0.5*(ego+.) + l2norm -> zallb. One wave/node.
__global__ void gather_norm_kernel(const int* __restrict__ rowptr, const int2* __restrict__ pack,
                                   const ushort* __restrict__ xb, const float* __restrict__ ue,
                                   const float* __restrict__ ie, ushort* __restrict__ zallb) {
  int n = blockIdx.x * 4 + (threadIdx.x >> 6);
  if (n >= N_NODES) return;
  int lane = threadIdx.x & 63;
  int k = rowptr[n], kend = rowptr[n + 1];
  float acc = 0.f;
  for (; k + 2 <= kend; k += 2) {
    int2 p0 = pack[k];
    int2 p1 = pack[k + 1];
    float x0 = bf2f(xb[(size_t)p0.x * DIM + lane]);
    float x1 = bf2f(xb[(size_t)p1.x * DIM + lane]);
    acc = fmaf(__int_as_float(p0.y), x0, acc);
    acc = fmaf(__int_as_float(p1.y), x1, acc);
  }
  if (k < kend) {
    int2 p = pack[k];
    acc = fmaf(__int_as_float(p.y), bf2f(xb[(size_t)p.x * DIM + lane]), acc);
  }
  const float* eg = ego_row(ue, ie, n);
  float v = 0.5f * (eg[lane] + acc);
  float ss = wave_reduce_sum(v * v);
  float z = v / fmaxf(sqrtf(ss), 1e-12f);
  zallb[(size_t)n * DIM + lane] = f2bf(z);
}

// ---------------- graph 1: fused filter + accumulate ----------------
// Per-block LDS compaction (no global counter, no flagged buffer), then the
// block's 4 waves immediately gather xb rows and atomic-accumulate into z1acc.
__global__ __launch_bounds__(256) void graph1_fused_kernel(
    const int* __restrict__ rows, const int* __restrict__ cols,
    const float* __restrict__ vals, const int* __restrict__ map,
    const ushort* __restrict__ xb, float* __restrict__ z1acc, int nE) {
  __shared__ int lcount;
  __shared__ int hcol[256];
  __shared__ float hval[256];
  __shared__ int hslot[256];
  int tid = threadIdx.x;
  if (tid == 0) lcount = 0;
  __syncthreads();
  int e = blockIdx.x * 256 + tid;
  if (e < nE) {
    int r = rows[e];
    int s = map[r];
    if (s >= 0) {
      int pos = atomicAdd(&lcount, 1);  // LDS atomic - block-local
      hcol[pos] = cols[e];
      hval[pos] = vals[e];
      hslot[pos] = s;
    }
  }
  __syncthreads();
  int n = lcount;
  int wave = tid >> 6, lane = tid & 63;
  for (int k = wave; k < n; k += 4) {
    int c = hcol[k];
    float v = hval[k];
    int s = hslot[k];
    float x = bf2f(xb[(size_t)c * DIM + lane]);
    unsafeAtomicAdd(&z1acc[(size_t)s * DIM + lane], v * x);
  }
}

// z1 normalize (fp32) -> bf16; pos term out -= dot(z1, z2) with z2 from zallb.
__global__ void gather1_kernel(const float* __restrict__ ue, const float* __restrict__ ie,
                               const int* __restrict__ nu, const int* __restrict__ ni,
                               const int* __restrict__ map, const float* __restrict__ z1acc,
                               const ushort* __restrict__ zallb, ushort* __restrict__ z1b,
                               float* __restrict__ out) {
  int s = blockIdx.x * 4 + (threadIdx.x >> 6);
  if (s >= SLOTS) return;
  int lane = threadIdx.x & 63;
  int n = (s < BATCH) ? nu[s] : (N_USERS + ni[s - BATCH]);
  int fs = map[n];
  const float* e = ego_row(ue, ie, n);
  float v = 0.5f * (e[lane] + z1acc[(size_t)fs * DIM + lane]);
  float ss = wave_reduce_sum(v * v);
  float z = v / fmaxf(sqrtf(ss), 1e-12f);
  z1b[(size_t)s * DIM + lane] = f2bf(z);
  float dp = wave_reduce_sum(z * bf2f(zallb[(size_t)n * DIM + lane]));
  if (lane == 0) atomicAdd(out, -dp);
}

// ---------------- ttl (bf16 MFMA) ----------------
// Wave tile: M=32 z1 rows x 16 j per chunk, K=64 -> 4 MFMAs/chunk.
// Block = 4 waves = 128 rows, one strip of 25 chunks (400 j). Grid 32x125.
#define TTL_STRIPS 125
#define TTL_CHUNKS 25
__global__ __launch_bounds__(256) void ttl_mfma_kernel(const ushort* __restrict__ z1b,
                                                       const ushort* __restrict__ zallb,
                                                       float* __restrict__ ttl) {
  int rb = blockIdx.x / TTL_STRIPS;
  int strip = blockIdx.x % TTL_STRIPS;
  int wave = threadIdx.x >> 6;
  int lane = threadIdx.x & 63;
  int r0 = rb * 128 + wave * 32;
  int side = r0 >> 11;  // rows 0..2047 users, 2048..4095 items
  const ushort* zs = zallb + (size_t)side * N_USERS * DIM;

  int m = lane & 15, q = lane >> 4;
  const ushort* ar0 = z1b + (size_t)(r0 + m) * DIM + q * 8;
  frag_ab a00 = *(const frag_ab*)ar0;
  frag_ab a01 = *(const frag_ab*)(ar0 + 32);
  const ushort* ar1 = ar0 + 16 * DIM;
  frag_ab a10 = *(const frag_ab*)ar1;
  frag_ab a11 = *(const frag_ab*)(ar1 + 32);

  int j0 = strip * (TTL_CHUNKS * 16);
  const ushort* bp = zs + (size_t)(j0 + m) * DIM + q * 8;

  // depth-2 register pipeline on B
  frag_ab b0c = *(const frag_ab*)bp;
  frag_ab b1c = *(const frag_ab*)(bp + 32);
  const ushort* bp1 = bp + 16 * DIM;
  frag_ab b0n = *(const frag_ab*)bp1;
  frag_ab b1n = *(const frag_ab*)(bp1 + 32);

  float racc[8] = {0.f, 0.f, 0.f, 0.f, 0.f, 0.f, 0.f, 0.f};

  for (int c = 0; c < TTL_CHUNKS; c++) {
    frag_ab b0f = b0c, b1f = b1c;
    if (c + 2 < TTL_CHUNKS) {
      const ushort* bp2 = bp + 2 * 16 * DIM;
      b0f = *(const frag_ab*)bp2;
      b1f = *(const frag_ab*)(bp2 + 32);
    }
    frag_cd acc0 = {}, acc1 = {};
    acc0 = __builtin_amdgcn_mfma_f32_16x16x32_bf16(a00, b0c, acc0, 0, 0, 0);
    acc0 = __builtin_amdgcn_mfma_f32_16x16x32_bf16(a01, b1c, acc0, 0, 0, 0);
    acc1 = __builtin_amdgcn_mfma_f32_16x16x32_bf16(a10, b0c, acc1, 0, 0, 0);
    acc1 = __builtin_amdgcn_mfma_f32_16x16x32_bf16(a11, b1c, acc1, 0, 0, 0);
#pragma unroll
    for (int r = 0; r < 4; r++) {
      racc[r] += __expf(2.f * acc0[r]);
      racc[4 + r] += __expf(2.f * acc1[r]);
    }
    b0c = b0n; b1c = b1n;
    b0n = b0f; b1n = b1f;
    bp += 16 * DIM;
  }

  // C layout: col(=zall j) = lane&15, row(=z1 row) = q*4+reg. Reduce over j lanes.
#pragma unroll
  for (int h = 0; h < 2; h++) {
#pragma unroll
    for (int r = 0; r < 4; r++) {
      float v = racc[h * 4 + r];
      v += __shfl_xor(v, 1, 64);
      v += __shfl_xor(v, 2, 64);
      v += __shfl_xor(v, 4, 64);
      v += __shfl_xor(v, 8, 64);
      if (m == 0) atomicAdd(&ttl[r0 + h * 16 + q * 4 + r], v);
    }
  }
}

// out += 0.5 * sum_i log(ttl[i])
__global__ void final_kernel(const float* __restrict__ ttl, float* __restrict__ out) {
  int t = blockIdx.x * blockDim.x + threadIdx.x;
  float v = (t < SLOTS) ? 0.5f * logf(ttl[t]) : 0.f;
  v = wave_reduce_sum(v);
  if ((threadIdx.x & 63) == 0) atomicAdd(out, v);
}

// ---------------- launch ----------------

extern "C" void kernel_launch(void* const* d_in, const int* in_sizes, int n_in,
                              void* d_out, int out_size, void* d_ws, size_t ws_size,
                              hipStream_t stream) {
  const float* ue = (const float*)d_in[0];
  const float* ie = (const float*)d_in[1];
  const int* rows1 = (const int*)d_in[2];
  const int* cols1 = (const int*)d_in[3];
  const float* vals1 = (const float*)d_in[4];
  const int* rows2 = (const int*)d_in[5];
  const int* cols2 = (const int*)d_in[6];
  const float* vals2 = (const float*)d_in[7];
  const int* nu = (const int*)d_in[8];
  const int* ni = (const int*)d_in[9];
  int nE1 = in_sizes[2], nE2 = in_sizes[5];

  // workspace carve-out (256B aligned), total ~45 MB
  char* ws = (char*)d_ws;
  size_t o = 0;
  auto carve = [&](size_t bytes) {
    char* p = ws + o;
    o += (bytes + 255) & ~(size_t)255;
    return p;
  };
  int* map = (int*)carve(N_NODES * 4);
  float* z1acc = (float*)carve((size_t)SLOTS * DIM * 4);
  float* ttl = (float*)carve(SLOTS * 4);
  ushort* zallb = (ushort*)carve((size_t)N_NODES * DIM * 2);
  ushort* z1b = (ushort*)carve((size_t)SLOTS * DIM * 2);
  ushort* xb = (ushort*)carve((size_t)N_NODES * DIM * 2);
  int* deg = (int*)carve(N_NODES * 4);
  int* rowptr = (int*)carve((N_NODES + 1) * 4);
  int* cursor = (int*)carve(N_NODES * 4);
  int* bsum = (int*)carve(128 * 4);
  int2* pack = (int2*)carve((size_t)nE2 * 8);
  float* out = (float*)d_out;

  const int NCHUNKS = (N_NODES + 1023) / 1024;  // 98

  hipMemsetAsync(map, 0xFF, N_NODES * 4, stream);  // -1
  hipMemsetAsync(z1acc, 0, (size_t)SLOTS * DIM * 4, stream);
  hipMemsetAsync(ttl, 0, SLOTS * 4, stream);
  hipMemsetAsync(deg, 0, N_NODES * 4, stream);
  hipMemsetAsync(out, 0, sizeof(float), stream);

  build_map_kernel<<<16, 256, 0, stream>>>(nu, ni, map);
  ego2bf_kernel<<<(N_NODES * DIM / 4 + 255) / 256, 256, 0, stream>>>(ue, ie, xb);
  hist_kernel<<<(nE2 + 255) / 256, 256, 0, stream>>>(rows2, deg, nE2);
  scan_p1_kernel<<<NCHUNKS, 256, 0, stream>>>(deg, bsum);
  scan_p2_kernel<<<1, 64, 0, stream>>>(bsum, NCHUNKS);
  scan_p3_kernel<<<NCHUNKS, 256, 0, stream>>>(deg, bsum, rowptr, cursor);
  scatter_kernel<<<(nE2 + 255) / 256, 256, 0, stream>>>(rows2, cols2, vals2, cursor, pack, nE2);
  gather_norm_kernel<<<(N_NODES + 3) / 4, 256, 0, stream>>>(rowptr, pack, xb, ue, ie, zallb);
  graph1_fused_kernel<<<(nE1 + 255) / 256, 256, 0, stream>>>(rows1, cols1, vals1, map, xb, z1acc, nE1);
  gather1_kernel<<<SLOTS / 4, 256, 0, stream>>>(ue, ie, nu, ni, map, z1acc, zallb, z1b, out);
  ttl_mfma_kernel<<<32 * TTL_STRIPS, 256, 0, stream>>>(z1b, zallb, ttl);
  final_kernel<<<16, 256, 0, stream>>>(ttl, out);
}

// Round 6
// 610.604 us; speedup vs baseline: 1.6323x; 1.0843x over previous
//
#include <hip/hip_runtime.h>
#include <hip/hip_bf16.h>
#include <math.h>

#define N_USERS 50000
#define N_ITEMS 50000
#define N_NODES 100000
#define DIM 64
#define BATCH 2048
#define SLOTS 4096

using frag_ab = __attribute__((ext_vector_type(8))) short;  // 8 bf16
using frag_cd = __attribute__((ext_vector_type(4))) float;  // 4 fp32

// ---------------- helpers ----------------

__device__ __forceinline__ float wave_reduce_sum(float v) {
#pragma unroll
  for (int off = 32; off > 0; off >>= 1)
    v += __shfl_xor(v, off, 64);
  return v;
}

__device__ __forceinline__ const float* ego_row(const float* ue, const float* ie, int n) {
  return (n < N_USERS) ? (ue + (size_t)n * DIM) : (ie + (size_t)(n - N_USERS) * DIM);
}

__device__ __forceinline__ ushort f2bf(float x) {
  __hip_bfloat16 h = __float2bfloat16(x);
  return *(ushort*)&h;
}

__device__ __forceinline__ float bf2f(ushort u) {
  return __uint_as_float(((unsigned)u) << 16);
}

// ---------------- small setup kernels ----------------

__global__ void build_map_kernel(const int* __restrict__ nu, const int* __restrict__ ni,
                                 int* __restrict__ map) {
  int s = blockIdx.x * blockDim.x + threadIdx.x;
  if (s >= SLOTS) return;
  int n = (s < BATCH) ? nu[s] : (N_USERS + ni[s - BATCH]);
  map[n] = s;
}

// ego -> bf16 (concatenated node-major table xb[100000][64])
__global__ void ego2bf_kernel(const float* __restrict__ ue, const float* __restrict__ ie,
                              ushort* __restrict__ xb) {
  int t = blockIdx.x * blockDim.x + threadIdx.x;  // index of float4 group
  const int TOT = N_NODES * DIM / 4;
  if (t >= TOT) return;
  const int UH = N_USERS * DIM / 4;
  float4 f = (t < UH) ? ((const float4*)ue)[t] : ((const float4*)ie)[t - UH];
  ushort4 o;
  o.x = f2bf(f.x); o.y = f2bf(f.y); o.z = f2bf(f.z); o.w = f2bf(f.w);
  ((ushort4*)xb)[t] = o;
}

// ---------------- graph 2: per-row linked list (no sort, no scatter) ----------

// next[e] written coalesced by e; head[] is 400KB of L2-resident atomics.
__global__ void link2_kernel(const int* __restrict__ rows, int* __restrict__ head,
                             int* __restrict__ next, int nE) {
  int e = blockIdx.x * blockDim.x + threadIdx.x;
  if (e >= nE) return;
  int r = rows[e];
  next[e] = atomicExch(&head[r], e);
}

// Wave-per-node chain walk: broadcast loads of cols/vals/next (L2/L3-resident),
// 128B xb row gather per edge; fp32 accumulate; fused 0.5*(ego+.)+l2norm -> zallb.
__global__ void gather_chain_norm_kernel(const int* __restrict__ head,
                                         const int* __restrict__ next,
                                         const int* __restrict__ cols,
                                         const float* __restrict__ vals,
                                         const ushort* __restrict__ xb,
                                         const float* __restrict__ ue,
                                         const float* __restrict__ ie,
                                         ushort* __restrict__ zallb) {
  int n = blockIdx.x * 4 + (threadIdx.x >> 6);
  if (n >= N_NODES) return;
  int lane = threadIdx.x & 63;
  float acc = 0.f;
  int e = head[n];
  while (e >= 0) {
    int c = cols[e];     // wave-broadcast
    float v = vals[e];   // wave-broadcast
    int en = next[e];    // wave-broadcast (the serial dependency)
    acc = fmaf(v, bf2f(xb[(size_t)c * DIM + lane]), acc);
    e = en;
  }
  const float* eg = ego_row(ue, ie, n);
  float w = 0.5f * (eg[lane] + acc);
  float ss = wave_reduce_sum(w * w);
  float z = w / fmaxf(sqrtf(ss), 1e-12f);
  zallb[(size_t)n * DIM + lane] = f2bf(z);
}

// ---------------- graph 1: fused filter + accumulate ----------------
// Per-block LDS compaction, then the block's 4 waves gather xb rows and
// atomic-accumulate into the L2-resident 1MB z1acc.
__global__ __launch_bounds__(256) void graph1_fused_kernel(
    const int* __restrict__ rows, const int* __restrict__ cols,
    const float* __restrict__ vals, const int* __restrict__ map,
    const ushort* __restrict__ xb, float* __restrict__ z1acc, int nE) {
  __shared__ int lcount;
  __shared__ int hcol[256];
  __shared__ float hval[256];
  __shared__ int hslot[256];
  int tid = threadIdx.x;
  if (tid == 0) lcount = 0;
  __syncthreads();
  int e = blockIdx.x * 256 + tid;
  if (e < nE) {
    int r = rows[e];
    int s = map[r];
    if (s >= 0) {
      int pos = atomicAdd(&lcount, 1);  // LDS atomic - block-local
      hcol[pos] = cols[e];
      hval[pos] = vals[e];
      hslot[pos] = s;
    }
  }
  __syncthreads();
  int n = lcount;
  int wave = tid >> 6, lane = tid & 63;
  for (int k = wave; k < n; k += 4) {
    int c = hcol[k];
    float v = hval[k];
    int s = hslot[k];
    float x = bf2f(xb[(size_t)c * DIM + lane]);
    unsafeAtomicAdd(&z1acc[(size_t)s * DIM + lane], v * x);
  }
}

// z1 normalize (fp32) -> bf16; pos term out -= dot(z1, z2) with z2 from zallb.
__global__ void gather1_kernel(const float* __restrict__ ue, const float* __restrict__ ie,
                               const int* __restrict__ nu, const int* __restrict__ ni,
                               const int* __restrict__ map, const float* __restrict__ z1acc,
                               const ushort* __restrict__ zallb, ushort* __restrict__ z1b,
                               float* __restrict__ out) {
  int s = blockIdx.x * 4 + (threadIdx.x >> 6);
  if (s >= SLOTS) return;
  int lane = threadIdx.x & 63;
  int n = (s < BATCH) ? nu[s] : (N_USERS + ni[s - BATCH]);
  int fs = map[n];
  const float* e = ego_row(ue, ie, n);
  float v = 0.5f * (e[lane] + z1acc[(size_t)fs * DIM + lane]);
  float ss = wave_reduce_sum(v * v);
  float z = v / fmaxf(sqrtf(ss), 1e-12f);
  z1b[(size_t)s * DIM + lane] = f2bf(z);
  float dp = wave_reduce_sum(z * bf2f(zallb[(size_t)n * DIM + lane]));
  if (lane == 0) atomicAdd(out, -dp);
}

// ---------------- ttl (bf16 MFMA) ----------------
// Wave tile: M=32 z1 rows x 16 j per chunk, K=64 -> 4 MFMAs/chunk.
// Block = 4 waves = 128 rows, one strip of 25 chunks (400 j). Grid 32x125.
#define TTL_STRIPS 125
#define TTL_CHUNKS 25
__global__ __launch_bounds__(256) void ttl_mfma_kernel(const ushort* __restrict__ z1b,
                                                       const ushort* __restrict__ zallb,
                                                       float* __restrict__ ttl) {
  int rb = blockIdx.x / TTL_STRIPS;
  int strip = blockIdx.x % TTL_STRIPS;
  int wave = threadIdx.x >> 6;
  int lane = threadIdx.x & 63;
  int r0 = rb * 128 + wave * 32;
  int side = r0 >> 11;  // rows 0..2047 users, 2048..4095 items
  const ushort* zs = zallb + (size_t)side * N_USERS * DIM;

  int m = lane & 15, q = lane >> 4;
  const ushort* ar0 = z1b + (size_t)(r0 + m) * DIM + q * 8;
  frag_ab a00 = *(const frag_ab*)ar0;
  frag_ab a01 = *(const frag_ab*)(ar0 + 32);
  const ushort* ar1 = ar0 + 16 * DIM;
  frag_ab a10 = *(const frag_ab*)ar1;
  frag_ab a11 = *(const frag_ab*)(ar1 + 32);

  int j0 = strip * (TTL_CHUNKS * 16);
  const ushort* bp = zs + (size_t)(j0 + m) * DIM + q * 8;

  // depth-2 register pipeline on B
  frag_ab b0c = *(const frag_ab*)bp;
  frag_ab b1c = *(const frag_ab*)(bp + 32);
  const ushort* bp1 = bp + 16 * DIM;
  frag_ab b0n = *(const frag_ab*)bp1;
  frag_ab b1n = *(const frag_ab*)(bp1 + 32);

  float racc[8] = {0.f, 0.f, 0.f, 0.f, 0.f, 0.f, 0.f, 0.f};

  for (int c = 0; c < TTL_CHUNKS; c++) {
    frag_ab b0f = b0c, b1f = b1c;
    if (c + 2 < TTL_CHUNKS) {
      const ushort* bp2 = bp + 2 * 16 * DIM;
      b0f = *(const frag_ab*)bp2;
      b1f = *(const frag_ab*)(bp2 + 32);
    }
    frag_cd acc0 = {}, acc1 = {};
    acc0 = __builtin_amdgcn_mfma_f32_16x16x32_bf16(a00, b0c, acc0, 0, 0, 0);
    acc0 = __builtin_amdgcn_mfma_f32_16x16x32_bf16(a01, b1c, acc0, 0, 0, 0);
    acc1 = __builtin_amdgcn_mfma_f32_16x16x32_bf16(a10, b0c, acc1, 0, 0, 0);
    acc1 = __builtin_amdgcn_mfma_f32_16x16x32_bf16(a11, b1c, acc1, 0, 0, 0);
#pragma unroll
    for (int r = 0; r < 4; r++) {
      racc[r] += __expf(2.f * acc0[r]);
      racc[4 + r] += __expf(2.f * acc1[r]);
    }
    b0c = b0n; b1c = b1n;
    b0n = b0f; b1n = b1f;
    bp += 16 * DIM;
  }

  // C layout: col(=zall j) = lane&15, row(=z1 row) = q*4+reg. Reduce over j lanes.
#pragma unroll
  for (int h = 0; h < 2; h++) {
#pragma unroll
    for (int r = 0; r < 4; r++) {
      float v = racc[h * 4 + r];
      v += __shfl_xor(v, 1, 64);
      v += __shfl_xor(v, 2, 64);
      v += __shfl_xor(v, 4, 64);
      v += __shfl_xor(v, 8, 64);
      if (m == 0) atomicAdd(&ttl[r0 + h * 16 + q * 4 + r], v);
    }
  }
}

// out += 0.5 * sum_i log(ttl[i])
__global__ void final_kernel(const float* __restrict__ ttl, float* __restrict__ out) {
  int t = blockIdx.x * blockDim.x + threadIdx.x;
  float v = (t < SLOTS) ? 0.5f * logf(ttl[t]) : 0.f;
  v = wave_reduce_sum(v);
  if ((threadIdx.x & 63) == 0) atomicAdd(out, v);
}

// ---------------- launch ----------------

extern "C" void kernel_launch(void* const* d_in, const int* in_sizes, int n_in,
                              void* d_out, int out_size, void* d_ws, size_t ws_size,
                              hipStream_t stream) {
  const float* ue = (const float*)d_in[0];
  const float* ie = (const float*)d_in[1];
  const int* rows1 = (const int*)d_in[2];
  const int* cols1 = (const int*)d_in[3];
  const float* vals1 = (const float*)d_in[4];
  const int* rows2 = (const int*)d_in[5];
  const int* cols2 = (const int*)d_in[6];
  const float* vals2 = (const float*)d_in[7];
  const int* nu = (const int*)d_in[8];
  const int* ni = (const int*)d_in[9];
  int nE1 = in_sizes[2], nE2 = in_sizes[5];

  // workspace carve-out (256B aligned), total ~36 MB
  char* ws = (char*)d_ws;
  size_t o = 0;
  auto carve = [&](size_t bytes) {
    char* p = ws + o;
    o += (bytes + 255) & ~(size_t)255;
    return p;
  };
  int* map = (int*)carve(N_NODES * 4);
  float* z1acc = (float*)carve((size_t)SLOTS * DIM * 4);
  float* ttl = (float*)carve(SLOTS * 4);
  ushort* zallb = (ushort*)carve((size_t)N_NODES * DIM * 2);
  ushort* z1b = (ushort*)carve((size_t)SLOTS * DIM * 2);
  ushort* xb = (ushort*)carve((size_t)N_NODES * DIM * 2);
  int* head = (int*)carve(N_NODES * 4);
  int* next = (int*)carve((size_t)nE2 * 4);
  float* out = (float*)d_out;

  hipMemsetAsync(map, 0xFF, N_NODES * 4, stream);   // -1
  hipMemsetAsync(head, 0xFF, N_NODES * 4, stream);  // -1
  hipMemsetAsync(z1acc, 0, (size_t)SLOTS * DIM * 4, stream);
  hipMemsetAsync(ttl, 0, SLOTS * 4, stream);
  hipMemsetAsync(out, 0, sizeof(float), stream);

  build_map_kernel<<<16, 256, 0, stream>>>(nu, ni, map);
  ego2bf_kernel<<<(N_NODES * DIM / 4 + 255) / 256, 256, 0, stream>>>(ue, ie, xb);
  link2_kernel<<<(nE2 + 255) / 256, 256, 0, stream>>>(rows2, head, next, nE2);
  gather_chain_norm_kernel<<<(N_NODES + 3) / 4, 256, 0, stream>>>(head, next, cols2, vals2, xb,
                                                                  ue, ie, zallb);
  graph1_fused_kernel<<<(nE1 + 255) / 256, 256, 0, stream>>>(rows1, cols1, vals1, map, xb, z1acc, nE1);
  gather1_kernel<<<SLOTS / 4, 256, 0, stream>>>(ue, ie, nu, ni, map, z1acc, zallb, z1b, out);
  ttl_mfma_kernel<<<32 * TTL_STRIPS, 256, 0, stream>>>(z1b, zallb, ttl);
  final_kernel<<<16, 256, 0, stream>>>(ttl, out);
}